// Round 9
// baseline (608.056 us; speedup 1.0000x reference)
//
#include <hip/hip_runtime.h>
#include <hip/hip_fp16.h>

#define N_ROWS 65536
#define D_COLS 1024
#define M_ROWS 32768
#define QROWS  16384   // rows per LDS pass (64KB f32, 2 blocks/CU)

using u32 = unsigned int;
using u16 = unsigned short;
typedef float f32x4 __attribute__((ext_vector_type(4)));   // native vecs for nontemporal
typedef int   i32x4 __attribute__((ext_vector_type(4)));

// ---- ws[0] = 0 (abs-max accumulator) ----
__global__ void init_ws_k(u32* ws) {
    if (threadIdx.x == 0 && blockIdx.x == 0) ws[0] = 0u;
}

// ---- 64x64-tile transpose+pack: packed[j][i] = (u16)idx[i][j] | (fp16(upd*scl) << 16) ----
__global__ __launch_bounds__(256) void t_pack_k(const int* __restrict__ idx,
                                                const float* __restrict__ upd,
                                                const float* __restrict__ scl,
                                                u32* __restrict__ packed) {
    __shared__ u32   sidx[64][65];
    __shared__ float supd[64][65];
    const int j0 = (int)(blockIdx.x & 15) * 64;   // 16 j-tiles
    const int i0 = (int)(blockIdx.x >> 4) * 64;   // 512 i-tiles
    const int t = threadIdx.x;

    {
        const int rr = t >> 2, c4 = t & 3;
        const int*   ip = idx + (size_t)(i0 + rr) * D_COLS + j0;
        const float* up = upd + (size_t)(i0 + rr) * D_COLS + j0;
        #pragma unroll
        for (int cq = 0; cq < 4; ++cq) {
            const int jc = cq * 16 + c4 * 4;
            const i32x4 iv = __builtin_nontemporal_load((const i32x4*)(ip + jc));
            const f32x4 uv = __builtin_nontemporal_load((const f32x4*)(up + jc));
            sidx[rr][jc] = (u32)iv.x; sidx[rr][jc+1] = (u32)iv.y;
            sidx[rr][jc+2] = (u32)iv.z; sidx[rr][jc+3] = (u32)iv.w;
            supd[rr][jc] = uv.x; supd[rr][jc+1] = uv.y;
            supd[rr][jc+2] = uv.z; supd[rr][jc+3] = uv.w;
        }
    }
    __syncthreads();

    {
        const int jj = t >> 2, seg = t & 3;
        const __half hs = __float2half(scl[j0 + jj]);   // exact fp16 scale
        u32 w[8];
        #pragma unroll
        for (int p = 0; p < 8; ++p) {
            const int r = seg * 8 + p;          // 8 rows per thread... (seg covers 4*8=32)
            const int r2 = seg * 16 + 2 * p;    // process 2 rows per slot -> 16 rows
            const __half hv0 = __hmul(__float2half(supd[r2][jj]), hs);
            const __half hv1 = __hmul(__float2half(supd[r2 + 1][jj]), hs);
            (void)r;
            const u32 lo = (sidx[r2][jj] & 0xffffu) |
                           ((u32)*reinterpret_cast<const u16*>(&hv0) << 16);
            const u32 hi = (sidx[r2 + 1][jj] & 0xffffu) |
                           ((u32)*reinterpret_cast<const u16*>(&hv1) << 16);
            w[p] = 0;  // placeholder, rewritten below
            w[p] = lo; // store pattern: interleave handled by index math below
            // we emit pairs directly:
            ((u32*)nullptr); // no-op
            // write both into a local pair buffer
            // (kept simple: we write lo/hi into w via two arrays)
            // -- replaced below --
            w[p] = lo; // w holds even rows; odd rows go in w2
            (void)hi;
        }
        // Simpler correct path: write 16 consecutive rows as 4 uint4 (u32 each row)
        u32 out16[16];
        #pragma unroll
        for (int p = 0; p < 16; ++p) {
            const int r = seg * 16 + p;
            const __half hv = __hmul(__float2half(supd[r][jj]), hs);
            out16[p] = (sidx[r][jj] & 0xffffu) |
                       ((u32)*reinterpret_cast<const u16*>(&hv) << 16);
        }
        u32* d = packed + (size_t)(j0 + jj) * M_ROWS + i0 + seg * 16;
        ((uint4*)d)[0] = uint4{out16[0],  out16[1],  out16[2],  out16[3]};
        ((uint4*)d)[1] = uint4{out16[4],  out16[5],  out16[6],  out16[7]};
        ((uint4*)d)[2] = uint4{out16[8],  out16[9],  out16[10], out16[11]};
        ((uint4*)d)[3] = uint4{out16[12], out16[13], out16[14], out16[15]};
    }
}

// ---- one block per column: load the 32768-entry scan ONCE into registers,
//      then 4 LDS passes (quarters): zero -> LDS atomics -> coalesced fp16 write. ----
__global__ __launch_bounds__(1024) void scatter_col_k(const u32* __restrict__ packed,
                                                      __half* __restrict__ sumT) {
    __shared__ float acc[QROWS];                  // 64 KB -> 2 blocks/CU
    const int j = (int)(blockIdx.x & 7) * 128 + (int)(blockIdx.x >> 3); // 1024%8==0
    const int tid = threadIdx.x;

    // load entire column scan: 32 u32 per thread (int4-vectorized, coalesced)
    const i32x4* col4 = (const i32x4*)(packed + (size_t)j * M_ROWS);
    i32x4 v[8];
    #pragma unroll
    for (int k = 0; k < 8; ++k) v[k] = col4[k * 1024 + tid];

    float4* acc4 = (float4*)acc;
    #pragma unroll 1
    for (int h = 0; h < 4; ++h) {
        for (int t = tid; t < QROWS / 4; t += 1024) acc4[t] = float4{0.f, 0.f, 0.f, 0.f};
        __syncthreads();
        #pragma unroll
        for (int k = 0; k < 8; ++k) {
            const u32 e[4] = {(u32)v[k].x, (u32)v[k].y, (u32)v[k].z, (u32)v[k].w};
            #pragma unroll
            for (int q = 0; q < 4; ++q) {
                const int r = (int)(e[q] & 0xffffu);
                if ((r >> 14) == h) {
                    const u16 hb = (u16)(e[q] >> 16);
                    atomicAdd(&acc[r & (QROWS - 1)],
                              __half2float(*reinterpret_cast<const __half*>(&hb)));
                }
            }
        }
        __syncthreads();
        __half2* dst = (__half2*)(sumT + (size_t)j * N_ROWS + h * QROWS);
        for (int t = tid; t < QROWS / 2; t += 1024)
            dst[t] = __floats2half2_rn(acc[2 * t], acc[2 * t + 1]);
        __syncthreads();
    }
}

// ---- 64x64 tiles: out = var*s + sumT^T; var via nt loads; fused abs-max ----
__global__ __launch_bounds__(256) void finalize_k(const int* __restrict__ var,
                                                  const __half* __restrict__ sumT,
                                                  const float* __restrict__ var_scale,
                                                  float* __restrict__ outf,
                                                  u32* __restrict__ ws) {
    __shared__ float sm[64][65];
    __shared__ float wmax[4];
    const int r0 = (int)(blockIdx.x >> 4) * 64;   // 1024 row-tiles
    const int j0 = (int)(blockIdx.x & 15) * 64;   // 16 col-tiles
    const int tid = threadIdx.x;
    const float s = var_scale[0];

    {
        const int jj = tid >> 2, seg = tid & 3;
        const __half* colp = sumT + (size_t)(j0 + jj) * N_ROWS + r0 + seg * 16;
        #pragma unroll
        for (int q = 0; q < 2; ++q) {
            const uint4 w = ((const uint4*)colp)[q];
            const u32 wv[4] = {w.x, w.y, w.z, w.w};
            #pragma unroll
            for (int i = 0; i < 4; ++i) {
                const __half2 hh = *reinterpret_cast<const __half2*>(&wv[i]);
                const float2 f = __half22float2(hh);
                const int rr = seg * 16 + q * 8 + i * 2;
                sm[rr][jj] = f.x;
                sm[rr + 1][jj] = f.y;
            }
        }
    }
    __syncthreads();

    float m = 0.f;
    #pragma unroll
    for (int k = 0; k < 4; ++k) {
        const int l = k * 256 + tid;              // 0..1023 int4 units
        const int rr = l >> 4, c4 = l & 15;
        const i32x4 v = __builtin_nontemporal_load(
            (const i32x4*)(var + (size_t)(r0 + rr) * D_COLS + j0) + c4);
        float4 o;
        o.x = (float)v.x * s + sm[rr][c4 * 4 + 0];
        o.y = (float)v.y * s + sm[rr][c4 * 4 + 1];
        o.z = (float)v.z * s + sm[rr][c4 * 4 + 2];
        o.w = (float)v.w * s + sm[rr][c4 * 4 + 3];
        ((float4*)(outf + (size_t)(r0 + rr) * D_COLS + j0))[c4] = o;
        m = fmaxf(m, fmaxf(fmaxf(fabsf(o.x), fabsf(o.y)),
                           fmaxf(fabsf(o.z), fabsf(o.w))));
    }
    for (int off = 32; off; off >>= 1) m = fmaxf(m, __shfl_xor(m, off));
    if ((tid & 63) == 0) wmax[tid >> 6] = m;
    __syncthreads();
    if (tid == 0) {
        m = fmaxf(fmaxf(wmax[0], wmax[1]), fmaxf(wmax[2], wmax[3]));
        atomicMax(ws, __float_as_uint(m));
    }
}

// ---- y = clip(rint(out * 127/max), -128, 127) stored as f32; write scale ----
__global__ __launch_bounds__(256) void quant_k(const float4* __restrict__ outf4,
                                               f32x4* __restrict__ y4,
                                               const u32* __restrict__ ws,
                                               float* __restrict__ scale_out, int n4) {
    const float mx = __uint_as_float(ws[0]);
    const float inv = 127.0f / mx;
    int gid = blockIdx.x * 256 + threadIdx.x;
    if (gid == 0) scale_out[0] = mx / 127.0f;
    const int stride = gridDim.x * 256;
    for (int i = gid; i < n4; i += stride) {
        float4 v = outf4[i];
        f32x4 o;
        o.x = fminf(fmaxf(rintf(v.x * inv), -128.f), 127.f);
        o.y = fminf(fmaxf(rintf(v.y * inv), -128.f), 127.f);
        o.z = fminf(fmaxf(rintf(v.z * inv), -128.f), 127.f);
        o.w = fminf(fmaxf(rintf(v.w * inv), -128.f), 127.f);
        __builtin_nontemporal_store(o, &y4[i]);   // y never re-read
    }
}

extern "C" void kernel_launch(void* const* d_in, const int* in_sizes, int n_in,
                              void* d_out, int out_size, void* d_ws, size_t ws_size,
                              hipStream_t stream) {
    const int*   var       = (const int*)d_in[0];     // int8 transported as int32
    const float* var_scale = (const float*)d_in[1];
    const int*   idx       = (const int*)d_in[2];
    const float* upd       = (const float*)d_in[3];   // fp16 transported as f32
    const float* scl       = (const float*)d_in[4];   // fp16 transported as f32

    float* y    = (float*)d_out;                      // y (f32) [N*D]
    float* outf = y + (size_t)N_ROWS * D_COLS;        // out (f32) [N*D]
    float* scale_out = y + 2 * (size_t)N_ROWS * D_COLS;

    // scratch packed into the (not-yet-written) y region: exactly 256 MB
    char* scratch = (char*)y;
    u32*    packed = (u32*)scratch;                             // 128 MB [D][M]
    __half* sumT   = (__half*)(scratch + (size_t)134217728);    // 128 MB [D][N]
    u32* ws = (u32*)d_ws;

    const int n4 = N_ROWS * D_COLS / 4;

    init_ws_k<<<1, 64, 0, stream>>>(ws);
    t_pack_k<<<8192, 256, 0, stream>>>(idx, upd, scl, packed);
    scatter_col_k<<<1024, 1024, 0, stream>>>(packed, sumT);
    finalize_k<<<16384, 256, 0, stream>>>(var, sumT, var_scale, outf, ws);
    quant_k<<<4096, 256, 0, stream>>>((const float4*)outf, (f32x4*)y, ws, scale_out, n4);
}